// Round 5
// baseline (153.176 us; speedup 1.0000x reference)
//
#include <hip/hip_runtime.h>
#include <hip/hip_bf16.h>

typedef unsigned short u16;
typedef unsigned int u32;
typedef unsigned long long u64;

#define NB 2048       // B
#define NMC 4         // MC
#define NU 20000      // U
#define ND 128        // DIN = DOUT
#define EPB 32        // edges per row = E/B

typedef __attribute__((ext_vector_type(8))) short bf16x8;
typedef __attribute__((ext_vector_type(4))) float f32x4;

__device__ __forceinline__ u32 pack_bf16(float a, float b) {
    __hip_bfloat162 h = __float22bfloat162_rn(make_float2(a, b));
    return *(u32*)&h;
}
__device__ __forceinline__ u16 f2bf(float f) {
    u32 x = __float_as_uint(f);
    return (u16)((x + 0x7fffu + ((x >> 16) & 1u)) >> 16);
}
__device__ __forceinline__ float wsum(float v) {
    #pragma unroll
    for (int off = 32; off; off >>= 1) v += __shfl_xor(v, off);
    return v;
}

// ---------------------------------------------------------------------------
// Prep: WT[mat][c][k] bf16  <-  W[k][c] f32, for {Wv_agg, Wk, Wq, Wv_ff}.
// ---------------------------------------------------------------------------
__global__ __launch_bounds__(256) void prep_wt(
    const float* __restrict__ Wv_agg, const float* __restrict__ Wk,
    const float* __restrict__ Wq, const float* __restrict__ Wv_ff,
    u16* __restrict__ WT)
{
    __shared__ float Wl[16 * ND];
    const int m = blockIdx.x >> 3;
    const int ks = (blockIdx.x & 7) * 16;
    const int t = threadIdx.x;

    const float* W = (m == 0) ? Wv_agg : (m == 1) ? Wk : (m == 2) ? Wq : Wv_ff;
    const float4* src = (const float4*)(W + ks * ND);
    float4* dst = (float4*)Wl;
    dst[t * 2] = src[t * 2];
    dst[t * 2 + 1] = src[t * 2 + 1];
    __syncthreads();

    const int c = t >> 1, kh = t & 1;
    float v[8];
    #pragma unroll
    for (int j = 0; j < 8; j++) v[j] = Wl[(kh * 8 + j) * ND + c];
    uint4 pk;
    pk.x = pack_bf16(v[0], v[1]);
    pk.y = pack_bf16(v[2], v[3]);
    pk.z = pack_bf16(v[4], v[5]);
    pk.w = pack_bf16(v[6], v[7]);
    *(uint4*)&WT[((size_t)(m * ND + c)) * ND + ks + kh * 8] = pk;
}

// ---------------------------------------------------------------------------
// Gathered GEMM via bf16 MFMA: out[r] = table[ids[r]] @ W
// Block 256 thr = 4 waves; tile 128x128; K in 2 passes of 64.
// embed output -> bf16, the six B-side products -> f32.
// ---------------------------------------------------------------------------
#define LDSK 72
#define EMBED_BLOCKS 157

__global__ __launch_bounds__(256) void gemm_all(
    const float* __restrict__ agg, const float* __restrict__ ff,
    const u16* __restrict__ WT,
    const int* __restrict__ uids, const int* __restrict__ nodes,
    u16* __restrict__ embed_bf,
    float* __restrict__ selfA, float* __restrict__ selfF,
    float* __restrict__ K0, float* __restrict__ K1,
    float* __restrict__ Q0, float* __restrict__ Q1)
{
    __shared__ u16 As[ND * LDSK];
    __shared__ u16 Bs[ND * LDSK];

    const int bx = blockIdx.x;
    const int t  = threadIdx.x;

    const float* table = agg; const int* ids = uids; int wtm = 0;
    float* outf = nullptr; u16* outb = nullptr;
    int M, r0;
    if (bx < EMBED_BLOCKS) {
        M = NU; r0 = bx * 128; outb = embed_bf;
    } else {
        int z = bx - EMBED_BLOCKS;
        int mode = z >> 4;
        r0 = (z & 15) * 128;
        M = NB; ids = nodes;
        switch (mode) {
            case 0: table = agg; wtm = 0; outf = selfA; break;
            case 1: table = agg; wtm = 1; outf = K0;    break;
            case 2: table = agg; wtm = 2; outf = Q0;    break;
            case 3: table = ff;  wtm = 3; outf = selfF; break;
            case 4: table = ff;  wtm = 1; outf = K1;    break;
            default: table = ff; wtm = 2; outf = Q1;    break;
        }
    }

    const int rs = t >> 1, hs = t & 1;
    int srow = r0 + rs;
    const int id = ids[srow < M ? srow : (M - 1)];
    const float* arow = table + (size_t)id * ND;
    const u16* wrow = WT + ((size_t)(wtm * ND + rs)) * ND;

    const int w = t >> 6, lane = t & 63, q = lane >> 4, li = lane & 15;

    f32x4 acc[2][8];
    #pragma unroll
    for (int i = 0; i < 2; i++)
        #pragma unroll
        for (int j = 0; j < 8; j++) acc[i][j] = (f32x4){0.f, 0.f, 0.f, 0.f};

    for (int pass = 0; pass < 2; pass++) {
        const int k0 = pass * 64;
        {
            const float4* asrc = (const float4*)(arow + k0 + hs * 32);
            #pragma unroll
            for (int i = 0; i < 4; i++) {
                float4 v0 = asrc[2 * i], v1 = asrc[2 * i + 1];
                uint4 pk;
                pk.x = pack_bf16(v0.x, v0.y);
                pk.y = pack_bf16(v0.z, v0.w);
                pk.z = pack_bf16(v1.x, v1.y);
                pk.w = pack_bf16(v1.z, v1.w);
                *(uint4*)&As[rs * LDSK + hs * 32 + i * 8] = pk;
            }
        }
        {
            const uint4* bsrc = (const uint4*)(wrow + k0 + hs * 32);
            #pragma unroll
            for (int i = 0; i < 4; i++)
                *(uint4*)&Bs[rs * LDSK + hs * 32 + i * 8] = bsrc[i];
        }
        __syncthreads();

        #pragma unroll
        for (int c = 0; c < 2; c++) {
            const int kk = c * 32 + q * 8;
            bf16x8 af[2], bfr[8];
            #pragma unroll
            for (int tr = 0; tr < 2; tr++)
                af[tr] = *(const bf16x8*)&As[(w * 32 + tr * 16 + li) * LDSK + kk];
            #pragma unroll
            for (int tc = 0; tc < 8; tc++)
                bfr[tc] = *(const bf16x8*)&Bs[(tc * 16 + li) * LDSK + kk];
            #pragma unroll
            for (int tr = 0; tr < 2; tr++)
                #pragma unroll
                for (int tc = 0; tc < 8; tc++)
                    acc[tr][tc] = __builtin_amdgcn_mfma_f32_16x16x32_bf16(
                        af[tr], bfr[tc], acc[tr][tc], 0, 0, 0);
        }
        __syncthreads();
    }

    // epilogue: C/D layout col=lane&15, row=quad*4+reg
    #pragma unroll
    for (int tr = 0; tr < 2; tr++) {
        const int rloc = w * 32 + tr * 16 + q * 4;
        #pragma unroll
        for (int r = 0; r < 4; r++) {
            const int row = r0 + rloc + r;
            if (row < M) {
                if (outb) {
                    #pragma unroll
                    for (int tc = 0; tc < 8; tc++)
                        outb[(size_t)row * ND + tc * 16 + li] = f2bf(acc[tr][tc][r]);
                } else {
                    #pragma unroll
                    for (int tc = 0; tc < 8; tc++)
                        outf[(size_t)row * ND + tc * 16 + li] = acc[tr][tc][r];
                }
            }
        }
    }
}

// ---------------------------------------------------------------------------
// Finalize: one 64-lane wave per row, zero LDS, zero barriers.
// Lane owns dims {2t, 2t+1}. Dedupe via shfl key-compare; counts via ballot;
// 14 butterfly reductions; softmax/attention computed redundantly per lane.
// ---------------------------------------------------------------------------
__global__ __launch_bounds__(64) void finalize(
    const int* __restrict__ layer_idx, const int* __restrict__ col_idx,
    const u16* __restrict__ embed_bf,
    const float* __restrict__ selfA, const float* __restrict__ selfF,
    const float* __restrict__ K0, const float* __restrict__ K1,
    const float* __restrict__ Q0, const float* __restrict__ Q1,
    const float* __restrict__ mu_w, float* __restrict__ out)
{
    const int b = blockIdx.x;
    const int t = threadIdx.x;          // lane 0..63

    // --- edge metadata in lanes 0..31 ---
    int l = 0, c = 0;
    if (t < EPB) {
        l = layer_idx[b * EPB + t];
        c = col_idx[b * EPB + t];
    }
    const u32 key = ((u32)l << 15) | (u32)c;      // c < 20000 < 2^15
    int dup = 0;
    #pragma unroll
    for (int j = 0; j < EPB; j++) {
        u32 kj = __shfl(key, j);
        dup |= (j < t && kj == key);
    }
    const int keep = (t < EPB) && !dup;
    float inv[NMC];
    #pragma unroll
    for (int m = 0; m < NMC; m++) {
        int cm = __popcll(__ballot(keep && (l == m)));
        inv[m] = cm > 0 ? 1.f / (float)cm : 0.f;
    }
    const u32 info = ((u32)c << 3) | ((u32)l << 1) | (u32)keep;

    // --- gather & accumulate neigh sums (2 dims per lane) ---
    float a0x = 0.f, a0y = 0.f, a1x = 0.f, a1y = 0.f;
    float a2x = 0.f, a2y = 0.f, a3x = 0.f, a3y = 0.f;
    #pragma unroll
    for (int e = 0; e < EPB; e++) {
        u32 inf = __shfl(info, e);                 // wave-uniform
        if (inf & 1u) {
            int ce = inf >> 3, le = (inf >> 1) & 3;
            u32 v = *(const u32*)&embed_bf[(size_t)ce * ND + 2 * t];
            float lo = __uint_as_float(v << 16);
            float hi = __uint_as_float(v & 0xffff0000u);
            switch (le) {
                case 0: a0x += lo; a0y += hi; break;
                case 1: a1x += lo; a1y += hi; break;
                case 2: a2x += lo; a2y += hi; break;
                default: a3x += lo; a3y += hi; break;
            }
        }
    }
    const float n0x = a0x * inv[0], n0y = a0y * inv[0];
    const float n1x = a1x * inv[1], n1y = a1y * inv[1];
    const float n2x = a2x * inv[2], n2y = a2y * inv[2];
    const float n3x = a3x * inv[3], n3y = a3y * inv[3];

    // --- linear loads (float2 per lane) ---
    const size_t base2 = (size_t)b * ND + 2 * t;
    float2 sA = *(const float2*)&selfA[base2];
    float2 sF = *(const float2*)&selfF[base2];
    float2 k0 = *(const float2*)&K0[base2];
    float2 k1 = *(const float2*)&K1[base2];
    float2 q0 = *(const float2*)&Q0[base2];
    float2 q1 = *(const float2*)&Q1[base2];
    float2 mu0 = *(const float2*)&mu_w[2 * t];
    float2 mu1 = *(const float2*)&mu_w[ND + 2 * t];

    // --- 14 reductions (each lane contributes its 2 dims) ---
    const float sn = wsum(sA.x * sA.x + sA.y * sA.y);
    const float ds = wsum(sA.x * mu0.x + sA.y * mu0.y);
    float nn[NMC], dn[NMC];
    nn[0] = wsum(n0x * n0x + n0y * n0y); dn[0] = wsum(n0x * mu1.x + n0y * mu1.y);
    nn[1] = wsum(n1x * n1x + n1y * n1y); dn[1] = wsum(n1x * mu1.x + n1y * mu1.y);
    nn[2] = wsum(n2x * n2x + n2y * n2y); dn[2] = wsum(n2x * mu1.x + n2y * mu1.y);
    nn[3] = wsum(n3x * n3x + n3y * n3y); dn[3] = wsum(n3x * mu1.x + n3y * mu1.y);
    const float s00 = wsum(k0.x * q0.x + k0.y * q0.y) * (1.f / 128.f);
    const float s01 = wsum(k0.x * q1.x + k0.y * q1.y) * (1.f / 128.f);
    const float s10 = wsum(k1.x * q0.x + k1.y * q0.y) * (1.f / 128.f);
    const float s11 = wsum(k1.x * q1.x + k1.y * q1.y) * (1.f / 128.f);

    // --- persona softmax coefficients (all lanes, identical) ---
    float sc[NMC], mx = -1e30f;
    #pragma unroll
    for (int m = 0; m < NMC; m++) {
        float nrm = fmaxf(sqrtf(sn + nn[m]), 1e-12f);
        sc[m] = (ds + dn[m]) / nrm;
        mx = fmaxf(mx, sc[m]);
    }
    float se = 0.f, ee[NMC];
    #pragma unroll
    for (int m = 0; m < NMC; m++) { ee[m] = expf(sc[m] - mx); se += ee[m]; }
    const float ise = 1.f / se;
    const float bc0 = ee[0] * ise, bc1 = ee[1] * ise;
    const float bc2 = ee[2] * ise, bc3 = ee[3] * ise;

    // --- 2x2 highway attention coefficients ---
    const float m0 = fmaxf(s00, s01), e00 = expf(s00 - m0), e01 = expf(s01 - m0);
    const float id0 = 1.f / (e00 + e01);
    const float c00 = e00 * id0, c01 = e01 * id0;
    const float m1 = fmaxf(s10, s11), e10 = expf(s10 - m1), e11 = expf(s11 - m1);
    const float id1 = 1.f / (e10 + e11);
    const float c10 = e10 * id1, c11 = e11 * id1;

    // --- combine, residual, ELU, store (2 dims) ---
    const float nsx = n0x * bc0 + n1x * bc1 + n2x * bc2 + n3x * bc3;
    const float nsy = n0y * bc0 + n1y * bc1 + n2y * bc2 + n3y * bc3;
    const float sa1x = (sA.x + nsx) * 0.5f, sa1y = (sA.y + nsy) * 0.5f;
    float o0x = 0.9f * sa1x + 0.1f * (c00 * sa1x + c01 * sF.x);
    float o0y = 0.9f * sa1y + 0.1f * (c00 * sa1y + c01 * sF.y);
    float o1x = 0.9f * sF.x + 0.1f * (c10 * sa1x + c11 * sF.x);
    float o1y = 0.9f * sF.y + 0.1f * (c10 * sa1y + c11 * sF.y);
    o0x = o0x > 0.f ? o0x : (expf(o0x) - 1.f);
    o0y = o0y > 0.f ? o0y : (expf(o0y) - 1.f);
    o1x = o1x > 0.f ? o1x : (expf(o1x) - 1.f);
    o1y = o1y > 0.f ? o1y : (expf(o1y) - 1.f);
    *(float2*)&out[base2] = make_float2(o0x, o0y);
    *(float2*)&out[(size_t)NB * ND + base2] = make_float2(o1x, o1y);
}

// ---------------------------------------------------------------------------
extern "C" void kernel_launch(void* const* d_in, const int* in_sizes, int n_in,
                              void* d_out, int out_size, void* d_ws, size_t ws_size,
                              hipStream_t stream) {
    const int* nodes  = (const int*)d_in[0];
    const int* uids   = (const int*)d_in[1];
    const int* layer  = (const int*)d_in[3];
    const int* col    = (const int*)d_in[4];
    const float* agg    = (const float*)d_in[5];
    const float* ff     = (const float*)d_in[6];
    const float* Wv_agg = (const float*)d_in[7];
    const float* Wv_ff  = (const float*)d_in[8];
    const float* Wk     = (const float*)d_in[9];
    const float* Wq     = (const float*)d_in[10];
    const float* mu     = (const float*)d_in[11];

    // ws layout: WT bf16 (128 KB), embed bf16 (5.12 MB), six f32 buffers
    u16*   WT       = (u16*)d_ws;
    u16*   embed_bf = WT + (size_t)4 * ND * ND;
    float* fbase    = (float*)(embed_bf + (size_t)NU * ND);
    float* selfA = fbase;
    float* selfF = selfA + (size_t)NB * ND;
    float* K0    = selfF + (size_t)NB * ND;
    float* K1    = K0 + (size_t)NB * ND;
    float* Q0    = K1 + (size_t)NB * ND;
    float* Q1    = Q0 + (size_t)NB * ND;

    float* out = (float*)d_out;

    prep_wt<<<32, 256, 0, stream>>>(Wv_agg, Wk, Wq, Wv_ff, WT);

    gemm_all<<<EMBED_BLOCKS + 6 * (NB / 128), 256, 0, stream>>>(
        agg, ff, WT, uids, nodes,
        embed_bf, selfA, selfF, K0, K1, Q0, Q1);

    finalize<<<NB, 64, 0, stream>>>(
        layer, col, embed_bf, selfA, selfF, K0, K1, Q0, Q1, mu, out);
}